// Round 3
// baseline (201.958 us; speedup 1.0000x reference)
//
#include <hip/hip_runtime.h>

// YOLO-v1 loss, N=4096, S=14, 30 ch/cell. ~176 MB in, 5 floats out.
// R5: coalesced LDS staging, but per-chunk full waitcnt drains -> 2.55 TB/s.
// R7: lane-per-cell one-shot, max MLP, but 120B-stride loads -> 64 distinct
//     lines per VMEM instr (8x request amplification) -> ~54us, ~2.3 TB/s.
// R8: coalesced AND pipelined. Chunk k+1's global loads (pred/tcls/tbox/obj,
//     all coalesced float4 streams, tcls UNGATED to stay pure) issue into
//     registers BEFORE computing chunk k from the wave-private LDS segment;
//     regs->LDS staging happens after compute. No barriers, no explicit
//     waitcnt -- compiler places counted vmcnt before the ds_writes and
//     lgkmcnt before the ds_reads, so loads get a full compute phase plus
//     16-waves/CU TLP of cover. DS pipe is in-order per wave, so
//     single-buffered segments are safe (reads of k precede writes of k+1).

#define CELLS   802816              // 4096 * 14 * 14
#define THREADS 256
#define NBLK    1024                // 4 blocks/CU, all resident
#define NWAVES  (NBLK * 4)          // 4096
#define CHUNK   32
#define CHUNKS  (CELLS / CHUNK)     // 25088 -> ~6.1 chunks/wave
#define L_COORD 5.0f
#define L_NOOBJ 0.5f

__global__ __launch_bounds__(THREADS, 4) void yolo_main(
    const float* __restrict__ pred,    // [CELLS][30]
    const float* __restrict__ tbox,    // [CELLS][4]
    const float* __restrict__ tcls,    // [CELLS][20]
    const int*   __restrict__ objmap,  // [CELLS]
    float4*      __restrict__ part)    // [NBLK]
{
    __shared__ float lds[4 * 960];     // 3840 B per wave: 32 cells x 30 floats
    __shared__ float red[4][4];

    const int tid  = threadIdx.x;
    const int wv   = tid >> 6;
    const int lane = tid & 63;
    float*  seg = &lds[wv * 960];
    float4* s4  = (float4*)seg;

    // cls-pass lane->piece mapping (piece i = float4 i of the chunk's tcls;
    // lane covers i = lane, lane+64, lane+128(<32); cell = i/5, ch = (i%5)*4)
    const int cc0 = lane / 5,   ch0 = (lane - cc0 * 5) * 4;
    const int i1  = lane + 64;
    const int cc1 = i1 / 5,     ch1 = (i1 - cc1 * 5) * 4;
    const int i2  = lane + 128;
    const int cc2 = (lane < 32) ? (i2 / 5) : 0;
    const int ch2 = (lane < 32) ? (i2 - cc2 * 5) * 4 : 0;
    const int bcell = lane >> 1;       // box pass: 2 lanes per cell
    const int box   = lane & 1;
    const float invS = 1.0f / 14.0f;

    float acc_reg = 0.f, acc_cont = 0.f, acc_noobj = 0.f, acc_cls = 0.f;

    int c = blockIdx.x * 4 + wv;       // wave-uniform chunk index

    // ---- prologue: load chunk c, stage pred into LDS ----
    {
        const float4* p4 = (const float4*)pred + (size_t)c * 240;
        const float4* t4 = (const float4*)tcls + (size_t)c * 160;
        const int*    ob = objmap + (size_t)c * CHUNK;
        float4 v0 = p4[lane], v1 = p4[i1], v2 = p4[i2], v3;
        if (lane < 48) v3 = p4[lane + 192];
        float4 t0 = t4[lane], t1 = t4[i1], t2;
        if (lane < 32) t2 = t4[i2];
        float4 tb = ((const float4*)tbox)[(size_t)c * CHUNK + bcell];
        int o0 = ob[cc0], o1 = ob[cc1], o2 = ob[cc2], ox = ob[bcell];

        s4[lane] = v0; s4[i1] = v1; s4[i2] = v2;
        if (lane < 48) s4[lane + 192] = v3;

        for (;;) {
            const int  cn = c + NWAVES;
            const bool hn = cn < CHUNKS;

            // ---- issue chunk cn's loads (coalesced, into registers) ----
            float4 nv0, nv1, nv2, nv3, nt0, nt1, nt2, ntb;
            int no0 = 0, no1 = 0, no2 = 0, nox = 0;
            if (hn) {
                const float4* np4 = (const float4*)pred + (size_t)cn * 240;
                const float4* nt4 = (const float4*)tcls + (size_t)cn * 160;
                const int*    nob = objmap + (size_t)cn * CHUNK;
                nv0 = np4[lane]; nv1 = np4[i1]; nv2 = np4[i2];
                if (lane < 48) nv3 = np4[lane + 192];
                nt0 = nt4[lane]; nt1 = nt4[i1];
                if (lane < 32) nt2 = nt4[i2];
                ntb = ((const float4*)tbox)[(size_t)cn * CHUNK + bcell];
                no0 = nob[cc0]; no1 = nob[cc1]; no2 = nob[cc2]; nox = nob[bcell];
            }

            // ---- compute chunk c from LDS (loads above still in flight) ----
            {   // cls loss: pieces gated on obj, tcls already in registers
                float cl = 0.f;
                if (o0) {
                    const float2 a = *(const float2*)&seg[cc0 * 30 + 10 + ch0];
                    const float2 b = *(const float2*)&seg[cc0 * 30 + 12 + ch0];
                    float d0 = a.x - t0.x, d1 = a.y - t0.y;
                    float d2 = b.x - t0.z, d3 = b.y - t0.w;
                    cl += d0*d0 + d1*d1 + d2*d2 + d3*d3;
                }
                if (o1) {
                    const float2 a = *(const float2*)&seg[cc1 * 30 + 10 + ch1];
                    const float2 b = *(const float2*)&seg[cc1 * 30 + 12 + ch1];
                    float d0 = a.x - t1.x, d1 = a.y - t1.y;
                    float d2 = b.x - t1.z, d3 = b.y - t1.w;
                    cl += d0*d0 + d1*d1 + d2*d2 + d3*d3;
                }
                if ((lane < 32) && o2) {
                    const float2 a = *(const float2*)&seg[cc2 * 30 + 10 + ch2];
                    const float2 b = *(const float2*)&seg[cc2 * 30 + 12 + ch2];
                    float d0 = a.x - t2.x, d1 = a.y - t2.y;
                    float d2 = b.x - t2.z, d3 = b.y - t2.w;
                    cl += d0*d0 + d1*d1 + d2*d2 + d3*d3;
                }
                acc_cls += cl;
            }
            {   // box pass: thread = (cell, box), partner via shfl_xor
                const float* pp = &seg[bcell * 30 + box * 5];
                float x = pp[0], y = pp[1], w = pp[2], h = pp[3], conf = pp[4];
                if (!ox) acc_noobj += conf * conf;

                float txc = tb.x * invS, tyc = tb.y * invS;
                float tx1 = txc - 0.5f * tb.z, ty1 = tyc - 0.5f * tb.w;
                float tx2 = txc + 0.5f * tb.z, ty2 = tyc + 0.5f * tb.w;
                float ta  = (tx2 - tx1) * (ty2 - ty1);

                float ax1 = x * invS - 0.5f * w, ay1 = y * invS - 0.5f * h;
                float ax2 = x * invS + 0.5f * w, ay2 = y * invS + 0.5f * h;
                float a1  = (ax2 - ax1) * (ay2 - ay1);
                float iw  = fmaxf(fminf(ax2, tx2) - fmaxf(ax1, tx1), 0.f);
                float ih  = fmaxf(fminf(ay2, ty2) - fmaxf(ay1, ty1), 0.f);
                float inter = iw * ih;
                float iou   = inter / (a1 + ta - inter);

                float iou_o = __shfl_xor(iou, 1);
                bool win = (box == 0) ? (iou > iou_o) : !(iou_o > iou);
                if (win && ox) {
                    float dx = x - tb.x, dy = y - tb.y;
                    float dw = sqrtf(w) - sqrtf(tb.z);
                    float dh = sqrtf(h) - sqrtf(tb.w);
                    acc_reg  += dx*dx + dy*dy + dw*dw + dh*dh;
                    float dc  = conf - iou;
                    acc_cont += dc * dc;
                }
            }

            if (!hn) break;

            // ---- stage chunk cn into LDS, rotate registers ----
            s4[lane] = nv0; s4[i1] = nv1; s4[i2] = nv2;
            if (lane < 48) s4[lane + 192] = nv3;
            t0 = nt0; t1 = nt1; t2 = nt2; tb = ntb;
            o0 = no0; o1 = no1; o2 = no2; ox = nox;
            c = cn;
        }
    }

    // ---- final reduction ----
    #pragma unroll
    for (int off = 32; off > 0; off >>= 1) {
        acc_reg   += __shfl_down(acc_reg,   off);
        acc_cont  += __shfl_down(acc_cont,  off);
        acc_noobj += __shfl_down(acc_noobj, off);
        acc_cls   += __shfl_down(acc_cls,   off);
    }
    if (lane == 0) {
        red[wv][0] = acc_reg;
        red[wv][1] = acc_cont;
        red[wv][2] = acc_noobj;
        red[wv][3] = acc_cls;
    }
    __syncthreads();
    if (tid == 0) {
        float4 p;
        p.x = red[0][0] + red[1][0] + red[2][0] + red[3][0];
        p.y = red[0][1] + red[1][1] + red[2][1] + red[3][1];
        p.z = red[0][2] + red[1][2] + red[2][2] + red[3][2];
        p.w = red[0][3] + red[1][3] + red[2][3] + red[3][3];
        part[blockIdx.x] = p;
    }
}

__global__ __launch_bounds__(1024) void yolo_reduce(
    const float4* __restrict__ part, float* __restrict__ out)
{
    __shared__ float red[16][4];
    float r = 0.f, c = 0.f, n = 0.f, cl = 0.f;
    for (int i = threadIdx.x; i < NBLK; i += 1024) {   // exactly 1 load
        float4 p = part[i];
        r += p.x; c += p.y; n += p.z; cl += p.w;
    }
    #pragma unroll
    for (int off = 32; off > 0; off >>= 1) {
        r  += __shfl_down(r,  off);
        c  += __shfl_down(c,  off);
        n  += __shfl_down(n,  off);
        cl += __shfl_down(cl, off);
    }
    const int wave = threadIdx.x >> 6, lane = threadIdx.x & 63;
    if (lane == 0) {
        red[wave][0] = r; red[wave][1] = c; red[wave][2] = n; red[wave][3] = cl;
    }
    __syncthreads();
    if (threadIdx.x == 0) {
        float R = 0.f, C = 0.f, Nn = 0.f, Cl = 0.f;
        #pragma unroll
        for (int w = 0; w < 16; ++w) {
            R += red[w][0]; C += red[w][1]; Nn += red[w][2]; Cl += red[w][3];
        }
        const float invN = 1.0f / 4096.0f;
        float reg   = L_COORD * R  * invN;
        float cont  =           C  * invN;
        float noobj = L_NOOBJ * Nn * invN;
        float cls   =           Cl * invN;
        out[0] = reg + cont + noobj + cls;
        out[1] = reg;
        out[2] = cont;
        out[3] = noobj;
        out[4] = cls;
    }
}

extern "C" void kernel_launch(void* const* d_in, const int* in_sizes, int n_in,
                              void* d_out, int out_size, void* d_ws, size_t ws_size,
                              hipStream_t stream) {
    const float* pred   = (const float*)d_in[0];
    const float* tbox   = (const float*)d_in[1];
    const float* tcls   = (const float*)d_in[2];
    const int*   objmap = (const int*)  d_in[3];
    float4* part = (float4*)d_ws;      // NBLK * 16 B = 16 KB, every slot written
    float*  out  = (float*)d_out;

    yolo_main<<<NBLK, THREADS, 0, stream>>>(pred, tbox, tcls, objmap, part);
    yolo_reduce<<<1, 1024, 0, stream>>>(part, out);
}